// Round 2
// baseline (13553.998 us; speedup 1.0000x reference)
//
#include <hip/hip_runtime.h>
#include <hip/hip_bf16.h>

#define BB 64
#define TT 512
#define CC 512
#define HH 512
#define G4 2048
#define TCH 64   // timesteps per xp chunk

using bf16 = __hip_bfloat16;
typedef short s16x8 __attribute__((ext_vector_type(8)));
typedef float f32x4 __attribute__((ext_vector_type(4)));

static __device__ __forceinline__ s16x8 ld8(const bf16* p) {
  return *reinterpret_cast<const s16x8*>(p);
}

__global__ void cast_w_kernel(const float* __restrict__ s, bf16* __restrict__ d, int n) {
  int stride = gridDim.x * blockDim.x;
  for (int i = blockIdx.x * blockDim.x + threadIdx.x; i < n; i += stride)
    d[i] = __float2bfloat16(s[i]);
}

__global__ void bias_kernel(const float* __restrict__ a, const float* __restrict__ b,
                            float* __restrict__ o, int n) {
  int i = blockIdx.x * blockDim.x + threadIdx.x;
  if (i < n) o[i] = a[i] + b[i];
}

__global__ void zero_h_kernel(bf16* __restrict__ hA, bf16* __restrict__ hB,
                              float* __restrict__ cb) {
  int i = blockIdx.x * blockDim.x + threadIdx.x;  // 32768 total
  bf16 z = __float2bfloat16(0.f);
  hA[i] = z;
  hB[i] = z;
  cb[i] = 0.f;
}

// x (B,C,T) f32 -> xT (B,T,C) bf16
__global__ void transpose_x_kernel(const float* __restrict__ x, bf16* __restrict__ xT) {
  __shared__ float tile[32][33];
  int b = blockIdx.z;
  int t0 = blockIdx.x * 32, c0 = blockIdx.y * 32;
  const float* xb = x + (size_t)b * CC * TT;
  for (int i = threadIdx.y; i < 32; i += 8)
    tile[i][threadIdx.x] = xb[(size_t)(c0 + i) * TT + t0 + threadIdx.x];
  __syncthreads();
  bf16* ob = xT + (size_t)b * TT * CC;
  for (int i = threadIdx.y; i < 32; i += 8)
    ob[(size_t)(t0 + i) * CC + c0 + threadIdx.x] = __float2bfloat16(tile[threadIdx.x][i]);
}

// xp[m][n] = sum_k A[arow][k] * W[n][k] + bias[n]  for a 64-timestep chunk [t0, t0+64)
// A: (B*T, 512) bf16 k-contig (row = b*512 + t); W: (2048, 512) bf16 k-contig
// m = b*64 + tt  (M = 4096), arow = b*512 + t0 + tt
// grid (16, 32), block 256 = 4 waves (2x2), tile 128x128.
__global__ __launch_bounds__(256) void proj_kernel(const bf16* __restrict__ A,
                                                   const bf16* __restrict__ W,
                                                   const float* __restrict__ bias,
                                                   float* __restrict__ xp, int t0) {
  int w = threadIdx.x >> 6, l = threadIdx.x & 63;
  int lr = l & 15, lk = (l >> 4) * 8;
  int m0 = blockIdx.y * 128 + (w >> 1) * 64;  // multiple of 64: one batch's 64-row band
  int q = m0 >> 6;                            // batch index
  int n0 = blockIdx.x * 128 + (w & 1) * 64;
  const bf16* Ab = A + ((size_t)q * TT + t0) * 512;
  f32x4 acc[4][4] = {};
  for (int k = lk; k < 512; k += 32) {
    s16x8 a[4], bfr[4];
#pragma unroll
    for (int i = 0; i < 4; ++i) a[i] = ld8(Ab + (size_t)(i * 16 + lr) * 512 + k);
#pragma unroll
    for (int i = 0; i < 4; ++i) bfr[i] = ld8(W + (size_t)(n0 + i * 16 + lr) * 512 + k);
#pragma unroll
    for (int mi = 0; mi < 4; ++mi)
#pragma unroll
      for (int ni = 0; ni < 4; ++ni)
        acc[mi][ni] = __builtin_amdgcn_mfma_f32_16x16x32_bf16(a[mi], bfr[ni], acc[mi][ni], 0, 0, 0);
  }
#pragma unroll
  for (int mi = 0; mi < 4; ++mi) {
#pragma unroll
    for (int ni = 0; ni < 4; ++ni) {
      int n = n0 + ni * 16 + lr;
      float bv = bias[n];
#pragma unroll
      for (int r = 0; r < 4; ++r) {
        int m = m0 + mi * 16 + (l >> 4) * 4 + r;
        xp[(size_t)m * G4 + n] = acc[mi][ni][r] + bv;
      }
    }
  }
}

// One timestep. grid 32 WGs (16 channels each), block 256 = 4 waves; wave w = gate w.
// gates = xp_chunk[b*64 + (t-t0), :] + h_in @ Whh^T; c update; h -> h_out (+ hs1 bf16 OR
// transposed f32 scatter into out2 (B,H,T)).
__global__ __launch_bounds__(256) void lstm_step_kernel(
    const bf16* __restrict__ Whh, const float* __restrict__ xp,
    const bf16* __restrict__ h_in, bf16* __restrict__ h_out,
    float* __restrict__ cbuf, bf16* __restrict__ hs1, float* __restrict__ out2, int t) {
  int tid = threadIdx.x;
  int w = tid >> 6, l = tid & 63;
  int ch0 = blockIdx.x * 16;
  int lr = l & 15, lk = (l >> 4) * 8;
  int tt = t & (TCH - 1);

  // Prefetch xp + c early (HBM latency hides under the GEMM).
  float xg[4][4], cv0[4];
#pragma unroll
  for (int j = 0; j < 4; ++j) {
    int i = tid + j * 256;
    int m = i >> 4, cc = i & 15, ch = ch0 + cc;
    const float* xr = xp + ((size_t)m * TCH + tt) * G4;
    xg[j][0] = xr[ch];
    xg[j][1] = xr[512 + ch];
    xg[j][2] = xr[1024 + ch];
    xg[j][3] = xr[1536 + ch];
    cv0[j] = cbuf[m * 512 + ch];
  }

  // GEMM: 64 batches x 16 gate-rows of this wave's gate (A=h_in, B=Whh rows; both L2-hot)
  f32x4 acc[4] = {};
  const bf16* Wg = Whh + ((size_t)w * 512 + ch0) * 512;
#pragma unroll
  for (int kq = 0; kq < 16; ++kq) {
    int k = kq * 32 + lk;
    s16x8 a[4];
#pragma unroll
    for (int i = 0; i < 4; ++i) a[i] = ld8(h_in + (size_t)(i * 16 + lr) * 512 + k);
    s16x8 b = ld8(Wg + (size_t)lr * 512 + k);
#pragma unroll
    for (int mi = 0; mi < 4; ++mi)
      acc[mi] = __builtin_amdgcn_mfma_f32_16x16x32_bf16(a[mi], b, acc[mi], 0, 0, 0);
  }

  // Exchange gate tiles across waves (wave w holds gate w for 64 b x 16 ch)
  __shared__ float Gs[4][64][17];
#pragma unroll
  for (int mi = 0; mi < 4; ++mi)
#pragma unroll
    for (int r = 0; r < 4; ++r)
      Gs[w][mi * 16 + (l >> 4) * 4 + r][lr] = acc[mi][r];
  __syncthreads();

  // Elementwise LSTM cell update
#pragma unroll
  for (int j = 0; j < 4; ++j) {
    int i = tid + j * 256;
    int m = i >> 4, cc = i & 15, ch = ch0 + cc;
    float gi = Gs[0][m][cc] + xg[j][0];
    float gf = Gs[1][m][cc] + xg[j][1];
    float gg = Gs[2][m][cc] + xg[j][2];
    float go = Gs[3][m][cc] + xg[j][3];
    gi = 1.f / (1.f + __expf(-gi));
    gf = 1.f / (1.f + __expf(-gf));
    gg = tanhf(gg);
    go = 1.f / (1.f + __expf(-go));
    float cv = gf * cv0[j] + gi * gg;
    cbuf[m * 512 + ch] = cv;
    float hv = go * tanhf(cv);
    h_out[m * 512 + ch] = __float2bfloat16(hv);
    if (hs1) hs1[((size_t)m * TT + t) * 512 + ch] = __float2bfloat16(hv);
    else     out2[((size_t)m * 512 + ch) * 512 + t] = hv;
  }
}

extern "C" void kernel_launch(void* const* d_in, const int* in_sizes, int n_in,
                              void* d_out, int out_size, void* d_ws, size_t ws_size,
                              hipStream_t stream) {
  const float* x    = (const float*)d_in[0];
  const float* Wih1 = (const float*)d_in[1];
  const float* Whh1 = (const float*)d_in[2];
  const float* bih1 = (const float*)d_in[3];
  const float* bhh1 = (const float*)d_in[4];
  const float* Wih2 = (const float*)d_in[5];
  const float* Whh2 = (const float*)d_in[6];
  const float* bih2 = (const float*)d_in[7];
  const float* bhh2 = (const float*)d_in[8];
  float* out = (float*)d_out;

  // Workspace layout (~104.3 MB total)
  const size_t MB = 1ull << 20;
  char* p = (char*)d_ws;
  bf16*  xT    = (bf16*)(p);                  // 32MB (B,T,C) bf16
  bf16*  hs1   = (bf16*)(p + 32 * MB);        // 32MB (B,T,H) bf16
  float* xp    = (float*)(p + 64 * MB);       // 32MB (B, 64, 4H) f32 chunk
  bf16*  W1i   = (bf16*)(p + 96 * MB);        // 2MB each
  bf16*  W1h   = (bf16*)(p + 98 * MB);
  bf16*  W2i   = (bf16*)(p + 100 * MB);
  bf16*  W2h   = (bf16*)(p + 102 * MB);
  float* bias1 = (float*)(p + 104 * MB);          // 8KB
  float* bias2 = (float*)(p + 104 * MB + 8192);   // 8KB
  bf16*  hA    = (bf16*)(p + 104 * MB + 16384);   // 64KB
  bf16*  hB    = (bf16*)(p + 104 * MB + 81920);   // 64KB
  float* cb    = (float*)(p + 104 * MB + 147456); // 128KB
  if (ws_size < 104 * MB + 147456 + 131072) return;  // graceful: needs ~104.3MB

  const int NW = 4 * HH * CC;  // 1048576 per weight matrix
  cast_w_kernel<<<1024, 256, 0, stream>>>(Wih1, W1i, NW);
  cast_w_kernel<<<1024, 256, 0, stream>>>(Whh1, W1h, NW);
  cast_w_kernel<<<1024, 256, 0, stream>>>(Wih2, W2i, NW);
  cast_w_kernel<<<1024, 256, 0, stream>>>(Whh2, W2h, NW);
  bias_kernel<<<8, 256, 0, stream>>>(bih1, bhh1, bias1, G4);
  bias_kernel<<<8, 256, 0, stream>>>(bih2, bhh2, bias2, G4);
  transpose_x_kernel<<<dim3(16, 16, 64), dim3(32, 8), 0, stream>>>(x, xT);

  // Layer 1
  zero_h_kernel<<<128, 256, 0, stream>>>(hA, hB, cb);
  for (int c = 0; c < TT / TCH; ++c) {
    proj_kernel<<<dim3(16, 32), 256, 0, stream>>>(xT, W1i, bias1, xp, c * TCH);
    for (int t = c * TCH; t < (c + 1) * TCH; ++t) {
      bf16* hi = (t & 1) ? hB : hA;
      bf16* ho = (t & 1) ? hA : hB;
      lstm_step_kernel<<<32, 256, 0, stream>>>(W1h, xp, hi, ho, cb, hs1, nullptr, t);
    }
  }

  // Layer 2 (h written directly transposed into out)
  zero_h_kernel<<<128, 256, 0, stream>>>(hA, hB, cb);
  for (int c = 0; c < TT / TCH; ++c) {
    proj_kernel<<<dim3(16, 32), 256, 0, stream>>>(hs1, W2i, bias2, xp, c * TCH);
    for (int t = c * TCH; t < (c + 1) * TCH; ++t) {
      bf16* hi = (t & 1) ? hB : hA;
      bf16* ho = (t & 1) ? hA : hB;
      lstm_step_kernel<<<32, 256, 0, stream>>>(W2h, xp, hi, ho, cb, nullptr, out, t);
    }
  }
}

// Round 3
// 10241.827 us; speedup vs baseline: 1.3234x; 1.3234x over previous
//
#include <hip/hip_runtime.h>
#include <hip/hip_bf16.h>

#define BB 64
#define TT 512
#define CC 512
#define HH 512

using bf16 = __hip_bfloat16;
typedef short s16x8 __attribute__((ext_vector_type(8)));
typedef float f32x4 __attribute__((ext_vector_type(4)));

static __device__ __forceinline__ s16x8 ld8(const bf16* p) {
  return *reinterpret_cast<const s16x8*>(p);
}

static __device__ __forceinline__ float sigm(float x) {
  return 1.f / (1.f + __expf(-x));
}
static __device__ __forceinline__ float tanh_fast(float x) {
  x = fminf(fmaxf(x, -20.f), 20.f);
  float e = __expf(2.f * x);
  return (e - 1.f) / (e + 1.f);
}

__global__ void cast_w_kernel(const float* __restrict__ s, bf16* __restrict__ d, int n) {
  int stride = gridDim.x * blockDim.x;
  for (int i = blockIdx.x * blockDim.x + threadIdx.x; i < n; i += stride)
    d[i] = __float2bfloat16(s[i]);
}

__global__ void zero_ws_kernel(float* __restrict__ p, int nwords) {
  int i = blockIdx.x * blockDim.x + threadIdx.x;
  if (i < nwords) p[i] = 0.f;
}

// x (B,C,T) f32 -> xT (T,B,C) bf16   (time-major: per-tick slab is contiguous 64KB)
__global__ void transpose_x_kernel(const float* __restrict__ x, bf16* __restrict__ xT) {
  __shared__ float tile[32][33];
  int b = blockIdx.z;
  int t0 = blockIdx.x * 32, c0 = blockIdx.y * 32;
  const float* xb = x + (size_t)b * CC * TT;
  for (int i = threadIdx.y; i < 32; i += 8)
    tile[i][threadIdx.x] = xb[(size_t)(c0 + i) * TT + t0 + threadIdx.x];
  __syncthreads();
  for (int i = threadIdx.y; i < 32; i += 8)
    xT[(size_t)(t0 + i) * (BB * CC) + (size_t)b * CC + c0 + threadIdx.x] =
        __float2bfloat16(tile[threadIdx.x][i]);
}

// Persistent 2-layer pipelined LSTM. 64 WGs x 256 threads (4 waves).
// WGs 0..31: layer 1 (tick u computes t=u); WGs 32..63: layer 2 (tick u computes t=u-1).
// Each WG owns 16 channels x 4 gates; wave g = gate g, N=16 rows, K=1024 = [in | h_prev].
// Weights live in 128 VGPRs/wave; c-state + bias in registers across all ticks.
__global__ __launch_bounds__(256, 1) void lstm_persist_kernel(
    const bf16* __restrict__ Wi1, const bf16* __restrict__ Wh1,
    const float* __restrict__ bih1, const float* __restrict__ bhh1,
    const bf16* __restrict__ Wi2, const bf16* __restrict__ Wh2,
    const float* __restrict__ bih2, const float* __restrict__ bhh2,
    const bf16* __restrict__ xT,   // (T, B, C) bf16
    bf16* __restrict__ h1buf,      // 2 x (B, 512) bf16 double buffer
    bf16* __restrict__ h2buf,      // 2 x (B, 512) bf16 double buffer
    float* __restrict__ out,       // (B, 512, T) f32
    unsigned* __restrict__ bar) {
  const int tid = threadIdx.x;
  const int g = tid >> 6;        // wave index = gate (i,f,g,o)
  const int l = tid & 63;
  const int lr = l & 15;
  const int lk = (l >> 4) * 8;
  const int layer = blockIdx.x >> 5;
  const int wg = blockIdx.x & 31;
  const int ch0 = wg * 16;

  const bf16* Wih = layer ? Wi2 : Wi1;
  const bf16* Whh = layer ? Wh2 : Wh1;
  const float* bih = layer ? bih2 : bih1;
  const float* bhh = layer ? bhh2 : bhh1;

  // Weight fragments in registers: 16 rows (gate g, channels ch0..ch0+15) x K=1024.
  s16x8 wi[16], wh[16];
  {
    const bf16* rowI = Wih + (size_t)(g * 512 + ch0 + lr) * 512 + lk;
    const bf16* rowH = Whh + (size_t)(g * 512 + ch0 + lr) * 512 + lk;
#pragma unroll
    for (int kq = 0; kq < 16; ++kq) {
      wi[kq] = ld8(rowI + kq * 32);
      wh[kq] = ld8(rowH + kq * 32);
    }
  }

  // Cell-update ownership: thread -> channel cc = tid&15 (fixed), batches (tid>>4)+16j.
  const int cc = tid & 15;
  const int ch = ch0 + cc;
  float bsum[4];
#pragma unroll
  for (int q = 0; q < 4; ++q) bsum[q] = bih[q * 512 + ch] + bhh[q * 512 + ch];
  float cst[4] = {0.f, 0.f, 0.f, 0.f};

  __shared__ float Gs[4][64][17];

  for (int u = 0; u <= TT; ++u) {
    const bool active = (layer == 0) ? (u < TT) : (u >= 1);
    if (active) {
      const int t = (layer == 0) ? u : u - 1;
      const bf16 *A0, *A1;
      bf16* hout;
      if (layer == 0) {
        A0 = xT + (size_t)t * (BB * CC);               // x(t)
        A1 = h1buf + (size_t)((t + 1) & 1) * (BB * HH); // h1(t-1)
        hout = h1buf + (size_t)(t & 1) * (BB * HH);
      } else {
        A0 = h1buf + (size_t)(t & 1) * (BB * HH);       // h1(t)
        A1 = h2buf + (size_t)((t + 1) & 1) * (BB * HH); // h2(t-1)
        hout = h2buf + (size_t)(t & 1) * (BB * HH);
      }

      f32x4 acc[4] = {};
#pragma unroll
      for (int kq = 0; kq < 16; ++kq) {
#pragma unroll
        for (int mi = 0; mi < 4; ++mi) {
          s16x8 a = ld8(A0 + (size_t)(mi * 16 + lr) * 512 + kq * 32 + lk);
          acc[mi] = __builtin_amdgcn_mfma_f32_16x16x32_bf16(a, wi[kq], acc[mi], 0, 0, 0);
        }
      }
#pragma unroll
      for (int kq = 0; kq < 16; ++kq) {
#pragma unroll
        for (int mi = 0; mi < 4; ++mi) {
          s16x8 a = ld8(A1 + (size_t)(mi * 16 + lr) * 512 + kq * 32 + lk);
          acc[mi] = __builtin_amdgcn_mfma_f32_16x16x32_bf16(a, wh[kq], acc[mi], 0, 0, 0);
        }
      }

      // Exchange gate tiles across waves (wave g holds gate g for 64 b x 16 ch).
#pragma unroll
      for (int mi = 0; mi < 4; ++mi)
#pragma unroll
        for (int r = 0; r < 4; ++r)
          Gs[g][mi * 16 + (l >> 4) * 4 + r][lr] = acc[mi][r];
      __syncthreads();

      // Cell update: 4 (batch, channel) elements per thread; c-state in registers.
#pragma unroll
      for (int j = 0; j < 4; ++j) {
        const int m = (tid >> 4) + j * 16;
        float gi = sigm(Gs[0][m][cc] + bsum[0]);
        float gf = sigm(Gs[1][m][cc] + bsum[1]);
        float gg = tanh_fast(Gs[2][m][cc] + bsum[2]);
        float go = sigm(Gs[3][m][cc] + bsum[3]);
        float cv = gf * cst[j] + gi * gg;
        cst[j] = cv;
        float hv = go * tanh_fast(cv);
        hout[m * 512 + ch] = __float2bfloat16(hv);
        if (layer) out[((size_t)m * 512 + ch) * 512 + t] = hv;
      }
    }

    // Grid barrier: monotonic device-scope counter. Release flushes this XCD's L2;
    // acquire poll invalidates L1/L2 so next tick reads fresh h across XCDs.
    __syncthreads();
    if (tid == 0) {
      __hip_atomic_fetch_add(bar, 1u, __ATOMIC_RELEASE, __HIP_MEMORY_SCOPE_AGENT);
      const unsigned target = (unsigned)(u + 1) * 64u;
      while (__hip_atomic_load(bar, __ATOMIC_ACQUIRE, __HIP_MEMORY_SCOPE_AGENT) < target) {
        __builtin_amdgcn_s_sleep(1);
      }
    }
    __syncthreads();
  }
}

extern "C" void kernel_launch(void* const* d_in, const int* in_sizes, int n_in,
                              void* d_out, int out_size, void* d_ws, size_t ws_size,
                              hipStream_t stream) {
  const float* x    = (const float*)d_in[0];
  const float* Wih1 = (const float*)d_in[1];
  const float* Whh1 = (const float*)d_in[2];
  const float* bih1 = (const float*)d_in[3];
  const float* bhh1 = (const float*)d_in[4];
  const float* Wih2 = (const float*)d_in[5];
  const float* Whh2 = (const float*)d_in[6];
  const float* bih2 = (const float*)d_in[7];
  const float* bhh2 = (const float*)d_in[8];
  float* out = (float*)d_out;

  // Workspace layout (~41 MB)
  const size_t MB = 1ull << 20;
  char* p = (char*)d_ws;
  bf16*     xT  = (bf16*)(p);                       // 32MB (T,B,C) bf16
  bf16*     W1i = (bf16*)(p + 32 * MB);             // 2MB each
  bf16*     W1h = (bf16*)(p + 34 * MB);
  bf16*     W2i = (bf16*)(p + 36 * MB);
  bf16*     W2h = (bf16*)(p + 38 * MB);
  bf16*     h1b = (bf16*)(p + 40 * MB);             // 128KB (2 x B x 512)
  bf16*     h2b = (bf16*)(p + 40 * MB + 131072);    // 128KB
  unsigned* bar = (unsigned*)(p + 40 * MB + 262144);
  if (ws_size < 40 * MB + 262144 + 4096) return;    // needs ~40.3MB

  const int NW = 4 * HH * CC;  // 1048576 elements per weight matrix
  cast_w_kernel<<<1024, 256, 0, stream>>>(Wih1, W1i, NW);
  cast_w_kernel<<<1024, 256, 0, stream>>>(Whh1, W1h, NW);
  cast_w_kernel<<<1024, 256, 0, stream>>>(Wih2, W2i, NW);
  cast_w_kernel<<<1024, 256, 0, stream>>>(Whh2, W2h, NW);
  transpose_x_kernel<<<dim3(16, 16, 64), dim3(32, 8), 0, stream>>>(x, xT);
  // zero h buffers + barrier word (266240 bytes = 66560 words)
  zero_ws_kernel<<<260, 256, 0, stream>>>((float*)(p + 40 * MB), 66560);

  lstm_persist_kernel<<<64, 256, 0, stream>>>(W1i, W1h, bih1, bhh1,
                                              W2i, W2h, bih2, bhh2,
                                              xT, h1b, h2b, out, bar);
}

// Round 4
// 6340.448 us; speedup vs baseline: 2.1377x; 1.6153x over previous
//
#include <hip/hip_runtime.h>
#include <hip/hip_bf16.h>

#define BB 64
#define TT 512
#define CC 512
#define HH 512

using bf16 = __hip_bfloat16;
typedef short s16x8 __attribute__((ext_vector_type(8)));
typedef float f32x4 __attribute__((ext_vector_type(4)));

static __device__ __forceinline__ s16x8 ld8(const bf16* p) {
  return *reinterpret_cast<const s16x8*>(p);
}

static __device__ __forceinline__ float sigm(float x) {
  return 1.f / (1.f + __expf(-x));
}
static __device__ __forceinline__ float tanh_fast(float x) {
  x = fminf(fmaxf(x, -20.f), 20.f);
  float e = __expf(2.f * x);
  return (e - 1.f) / (e + 1.f);
}

__global__ void cast_w_kernel(const float* __restrict__ s, bf16* __restrict__ d, int n) {
  int stride = gridDim.x * blockDim.x;
  for (int i = blockIdx.x * blockDim.x + threadIdx.x; i < n; i += stride)
    d[i] = __float2bfloat16(s[i]);
}

__global__ void zero_ws_kernel(unsigned* __restrict__ p, int nwords) {
  int i = blockIdx.x * blockDim.x + threadIdx.x;
  if (i < nwords) p[i] = 0u;
}

// x (B,C,T) f32 -> xT (T,B,C) bf16   (time-major: per-tick slab contiguous 64KB)
__global__ void transpose_x_kernel(const float* __restrict__ x, bf16* __restrict__ xT) {
  __shared__ float tile[32][33];
  int b = blockIdx.z;
  int t0 = blockIdx.x * 32, c0 = blockIdx.y * 32;
  const float* xb = x + (size_t)b * CC * TT;
  for (int i = threadIdx.y; i < 32; i += 8)
    tile[i][threadIdx.x] = xb[(size_t)(c0 + i) * TT + t0 + threadIdx.x];
  __syncthreads();
  for (int i = threadIdx.y; i < 32; i += 8)
    xT[(size_t)(t0 + i) * (BB * CC) + (size_t)b * CC + c0 + threadIdx.x] =
        __float2bfloat16(tile[threadIdx.x][i]);
}

// Persistent pipelined 2-layer LSTM, producer-consumer flags (no grid barrier).
// 128 WGs x 256 thr (4 waves). WG id: layer = bx>>6, beta(batch half) = (bx>>5)&1,
// chg = bx&31 -> 16 channels. Wave g = gate g: rows = gate g, ch0..ch0+15; M = 32 batches.
// Weights (2 x 16 frags x 16B) pinned in VGPRs via asm. h1/h2 are write-once per-tick
// history buffers: producers store with agent-scope relaxed atomics (write-through),
// consumers use plain cached loads (lines never stale), ordering via vmcnt + relaxed
// flag fetch_add. flag[layer][beta][t] counts 32 ch-group producers.
__global__ __launch_bounds__(256, 1) void lstm_persist_kernel(
    const bf16* __restrict__ Wi1, const bf16* __restrict__ Wh1,
    const float* __restrict__ bih1, const float* __restrict__ bhh1,
    const bf16* __restrict__ Wi2, const bf16* __restrict__ Wh2,
    const float* __restrict__ bih2, const float* __restrict__ bhh2,
    const bf16* __restrict__ xT,   // (T, B, C) bf16
    bf16* __restrict__ h1h,        // (T, B, H) bf16 history
    bf16* __restrict__ h2h,        // (T, B, H) bf16 history
    float* __restrict__ out,       // (B, H, T) f32
    unsigned* __restrict__ flags)  // [2][2][512] u32, zeroed
{
  const int tid = threadIdx.x;
  const int g = tid >> 6, l = tid & 63;
  const int lr = l & 15, lk = (l >> 4) * 8;
  const int layer = blockIdx.x >> 6;
  const int beta = (blockIdx.x >> 5) & 1;
  const int ch0 = (blockIdx.x & 31) * 16;
  const int b0 = beta * 32;

  const bf16* WA = layer ? Wi2 : Wi1;   // multiplies A0 (x(t) or h1(t))
  const bf16* WB = layer ? Wh2 : Wh1;   // multiplies A1 (h_prev(t-1))
  const float* bi = layer ? bih2 : bih1;
  const float* bh = layer ? bhh2 : bhh1;

  // Weight fragments: 16 rows (gate g, ch0..ch0+15) x K=512, twice (WA, WB).
  s16x8 wa[16], wb[16];
  {
    const bf16* rowA = WA + (size_t)(g * 512 + ch0 + lr) * 512 + lk;
    const bf16* rowB = WB + (size_t)(g * 512 + ch0 + lr) * 512 + lk;
#pragma unroll
    for (int kq = 0; kq < 16; ++kq) {
      wa[kq] = ld8(rowA + kq * 32);
      wb[kq] = ld8(rowB + kq * 32);
    }
  }

  // Cell-update ownership: thread -> batch m = b0 + (tid>>3), channel pair q2 = (tid&7)*2.
  const int mloc = tid >> 3;
  const int m = b0 + mloc;
  const int q2 = (tid & 7) * 2;
  float bs[4][2];
#pragma unroll
  for (int gg = 0; gg < 4; ++gg)
#pragma unroll
    for (int k = 0; k < 2; ++k)
      bs[gg][k] = bi[gg * 512 + ch0 + q2 + k] + bh[gg * 512 + ch0 + q2 + k];
  float cst[2] = {0.f, 0.f};

  unsigned* fl_own = flags + ((size_t)layer * 2 + beta) * 512;   // this WG increments
  unsigned* fl_l1  = flags + (size_t)beta * 512;                 // layer-1 flags, same beta

  __shared__ float Gs[4][32][17];

  for (int t = 0; t < TT; ++t) {
    // Pin weights in registers (blocks remat/sinking of the pre-loop loads).
#pragma unroll
    for (int kq = 0; kq < 16; ++kq) {
      asm volatile("" : "+v"(wa[kq]));
      asm volatile("" : "+v"(wb[kq]));
    }

    // Wait for producers (fine-grained flags; relaxed agent loads, no cache ops).
    if (tid == 0) {
      if (layer == 0) {
        if (t > 0)
          while (__hip_atomic_load(fl_own + (t - 1), __ATOMIC_RELAXED, __HIP_MEMORY_SCOPE_AGENT) < 32u)
            __builtin_amdgcn_s_sleep(1);
      } else {
        while (__hip_atomic_load(fl_l1 + t, __ATOMIC_RELAXED, __HIP_MEMORY_SCOPE_AGENT) < 32u)
          __builtin_amdgcn_s_sleep(1);
        if (t > 0)
          while (__hip_atomic_load(fl_own + (t - 1), __ATOMIC_RELAXED, __HIP_MEMORY_SCOPE_AGENT) < 32u)
            __builtin_amdgcn_s_sleep(1);
      }
    }
    __syncthreads();

    // GEMM: acc[mi] over M=32 (two 16-row tiles), K=512 (A0) + K=512 (A1, skip t=0).
    const bf16* A0 = layer ? (h1h + (size_t)t * (BB * HH)) : (xT + (size_t)t * (BB * CC));
    f32x4 acc[2] = {};
#pragma unroll
    for (int kq = 0; kq < 16; ++kq) {
#pragma unroll
      for (int mi = 0; mi < 2; ++mi) {
        s16x8 a = ld8(A0 + (size_t)(b0 + mi * 16 + lr) * 512 + kq * 32 + lk);
        acc[mi] = __builtin_amdgcn_mfma_f32_16x16x32_bf16(a, wa[kq], acc[mi], 0, 0, 0);
      }
    }
    if (t > 0) {
      const bf16* A1 = (layer ? h2h : h1h) + (size_t)(t - 1) * (BB * HH);
#pragma unroll
      for (int kq = 0; kq < 16; ++kq) {
#pragma unroll
        for (int mi = 0; mi < 2; ++mi) {
          s16x8 a = ld8(A1 + (size_t)(b0 + mi * 16 + lr) * 512 + kq * 32 + lk);
          acc[mi] = __builtin_amdgcn_mfma_f32_16x16x32_bf16(a, wb[kq], acc[mi], 0, 0, 0);
        }
      }
    }

    // Exchange gate tiles across waves: wave g holds gate g for 32 b x 16 ch.
#pragma unroll
    for (int mi = 0; mi < 2; ++mi)
#pragma unroll
      for (int r = 0; r < 4; ++r)
        Gs[g][mi * 16 + (l >> 4) * 4 + r][lr] = acc[mi][r];
    __syncthreads();

    // Cell update: 2 channels of one batch per thread; c-state in registers.
    bf16* hout = (layer ? h2h : h1h) + (size_t)t * (BB * HH);
    union { ushort u[2]; unsigned v; } pk;
#pragma unroll
    for (int k = 0; k < 2; ++k) {
      int cc = q2 + k;
      float gi = sigm(Gs[0][mloc][cc] + bs[0][k]);
      float gf = sigm(Gs[1][mloc][cc] + bs[1][k]);
      float gg = tanh_fast(Gs[2][mloc][cc] + bs[2][k]);
      float go = sigm(Gs[3][mloc][cc] + bs[3][k]);
      float cv = gf * cst[k] + gi * gg;
      cst[k] = cv;
      float hvf = go * tanh_fast(cv);
      bf16 hb = __float2bfloat16(hvf);
      pk.u[k] = *reinterpret_cast<ushort*>(&hb);
      if (layer) out[((size_t)m * 512 + ch0 + cc) * 512 + t] = hvf;  // cached, write-once
    }
    // h square: 4B agent-scope write-through store (visible at coherence point).
    __hip_atomic_store((unsigned*)(hout + (size_t)m * 512 + ch0 + q2), pk.v,
                       __ATOMIC_RELAXED, __HIP_MEMORY_SCOPE_AGENT);

    // Drain this wave's vmem stores, then one flag increment per WG (relaxed: no wbl2).
    asm volatile("s_waitcnt vmcnt(0)" ::: "memory");
    __syncthreads();
    if (tid == 0)
      __hip_atomic_fetch_add(fl_own + t, 1u, __ATOMIC_RELAXED, __HIP_MEMORY_SCOPE_AGENT);
  }
}

extern "C" void kernel_launch(void* const* d_in, const int* in_sizes, int n_in,
                              void* d_out, int out_size, void* d_ws, size_t ws_size,
                              hipStream_t stream) {
  const float* x    = (const float*)d_in[0];
  const float* Wih1 = (const float*)d_in[1];
  const float* Whh1 = (const float*)d_in[2];
  const float* bih1 = (const float*)d_in[3];
  const float* bhh1 = (const float*)d_in[4];
  const float* Wih2 = (const float*)d_in[5];
  const float* Whh2 = (const float*)d_in[6];
  const float* bih2 = (const float*)d_in[7];
  const float* bhh2 = (const float*)d_in[8];
  float* out = (float*)d_out;

  // Workspace layout (~104 MB + 8KB flags)
  const size_t MB = 1ull << 20;
  char* p = (char*)d_ws;
  bf16*     xT    = (bf16*)(p);               // 32MB (T,B,C)
  bf16*     h1h   = (bf16*)(p + 32 * MB);     // 32MB (T,B,H) history
  bf16*     h2h   = (bf16*)(p + 64 * MB);     // 32MB (T,B,H) history
  bf16*     W1i   = (bf16*)(p + 96 * MB);     // 2MB each
  bf16*     W1h   = (bf16*)(p + 98 * MB);
  bf16*     W2i   = (bf16*)(p + 100 * MB);
  bf16*     W2h   = (bf16*)(p + 102 * MB);
  unsigned* flags = (unsigned*)(p + 104 * MB);  // [2][2][512] u32 = 8KB
  if (ws_size < 104 * MB + 8192) return;

  const int NW = 4 * HH * CC;  // 1048576 elements per weight matrix
  cast_w_kernel<<<1024, 256, 0, stream>>>(Wih1, W1i, NW);
  cast_w_kernel<<<1024, 256, 0, stream>>>(Whh1, W1h, NW);
  cast_w_kernel<<<1024, 256, 0, stream>>>(Wih2, W2i, NW);
  cast_w_kernel<<<1024, 256, 0, stream>>>(Whh2, W2h, NW);
  transpose_x_kernel<<<dim3(16, 16, 64), dim3(32, 8), 0, stream>>>(x, xT);
  zero_ws_kernel<<<8, 256, 0, stream>>>(flags, 2048);

  lstm_persist_kernel<<<128, 256, 0, stream>>>(W1i, W1h, bih1, bhh1,
                                               W2i, W2h, bih2, bhh2,
                                               xT, h1h, h2h, out, flags);
}

// Round 5
// 6079.056 us; speedup vs baseline: 2.2296x; 1.0430x over previous
//
#include <hip/hip_runtime.h>
#include <hip/hip_bf16.h>

#define BB 64
#define TT 512
#define CC 512
#define HH 512

using bf16 = __hip_bfloat16;
typedef short s16x8 __attribute__((ext_vector_type(8)));
typedef float f32x4 __attribute__((ext_vector_type(4)));

static __device__ __forceinline__ s16x8 ld8(const bf16* p) {
  return *reinterpret_cast<const s16x8*>(p);
}

static __device__ __forceinline__ float sigm(float x) {
  return 1.f / (1.f + __expf(-x));
}
static __device__ __forceinline__ float tanh_fast(float x) {
  x = fminf(fmaxf(x, -20.f), 20.f);
  float e = __expf(2.f * x);
  return (e - 1.f) / (e + 1.f);
}

__global__ void cast_w_kernel(const float* __restrict__ s, bf16* __restrict__ d, int n) {
  int stride = gridDim.x * blockDim.x;
  for (int i = blockIdx.x * blockDim.x + threadIdx.x; i < n; i += stride)
    d[i] = __float2bfloat16(s[i]);
}

__global__ void zero_ws_kernel(unsigned* __restrict__ p, int nwords) {
  int i = blockIdx.x * blockDim.x + threadIdx.x;
  if (i < nwords) p[i] = 0u;
}

// x (B,C,T) f32 -> xT (T,B,C) bf16   (time-major: per-tick slab contiguous 64KB)
__global__ void transpose_x_kernel(const float* __restrict__ x, bf16* __restrict__ xT) {
  __shared__ float tile[32][33];
  int b = blockIdx.z;
  int t0 = blockIdx.x * 32, c0 = blockIdx.y * 32;
  const float* xb = x + (size_t)b * CC * TT;
  for (int i = threadIdx.y; i < 32; i += 8)
    tile[i][threadIdx.x] = xb[(size_t)(c0 + i) * TT + t0 + threadIdx.x];
  __syncthreads();
  for (int i = threadIdx.y; i < 32; i += 8)
    xT[(size_t)(t0 + i) * (BB * CC) + (size_t)b * CC + c0 + threadIdx.x] =
        __float2bfloat16(tile[threadIdx.x][i]);
}

// Persistent pipelined 2-layer LSTM, producer-consumer sync via per-producer flag
// STORES (no RMW). 128 WGs x 256 thr (4 waves). WG: layer = bx>>6, beta = (bx>>5)&1,
// ch-group = bx&31 (16 channels). Wave g = gate g, M = 32 batches (beta half), K = 1024.
// flags[gang][producer]: producer WG's lane 0 stores t+1 (relaxed, agent scope) after its
// h-slab stores drain (vmcnt 0). Consumers: every wave polls the gang's 32 words with one
// coalesced load (lane i -> word i) + __any. h1/h2 are write-once (T,B,H) history buffers:
// producer h-stores are agent-scope relaxed atomics (write-through), consumer loads plain.
__global__ __launch_bounds__(256, 1) void lstm_persist_kernel(
    const bf16* __restrict__ Wi1, const bf16* __restrict__ Wh1,
    const float* __restrict__ bih1, const float* __restrict__ bhh1,
    const bf16* __restrict__ Wi2, const bf16* __restrict__ Wh2,
    const float* __restrict__ bih2, const float* __restrict__ bhh2,
    const bf16* __restrict__ xT,   // (T, B, C) bf16
    bf16* __restrict__ h1h,        // (T, B, H) bf16 history
    bf16* __restrict__ h2h,        // (T, B, H) bf16 history
    float* __restrict__ out,       // (B, H, T) f32
    unsigned* __restrict__ flags)  // [2][2][32] u32, zeroed
{
  const int tid = threadIdx.x;
  const int g = tid >> 6, l = tid & 63;
  const int lr = l & 15, lk = (l >> 4) * 8;
  const int layer = blockIdx.x >> 6;
  const int beta = (blockIdx.x >> 5) & 1;
  const int ch0 = (blockIdx.x & 31) * 16;
  const int b0 = beta * 32;

  const bf16* WA = layer ? Wi2 : Wi1;   // multiplies A0 (x(t) or h1(t))
  const bf16* WB = layer ? Wh2 : Wh1;   // multiplies A1 (h_prev(t-1))
  const float* bi = layer ? bih2 : bih1;
  const float* bh = layer ? bhh2 : bhh1;

  // Weight fragments: 16 rows (gate g, ch0..ch0+15) x K=512, twice (WA, WB).
  // Compiler may keep in VGPRs or re-load per tick from L2 — both fine.
  s16x8 wa[16], wb[16];
  {
    const bf16* rowA = WA + (size_t)(g * 512 + ch0 + lr) * 512 + lk;
    const bf16* rowB = WB + (size_t)(g * 512 + ch0 + lr) * 512 + lk;
#pragma unroll
    for (int kq = 0; kq < 16; ++kq) {
      wa[kq] = ld8(rowA + kq * 32);
      wb[kq] = ld8(rowB + kq * 32);
    }
  }

  // Cell-update ownership: thread -> batch m = b0 + (tid>>3), channel pair q2 = (tid&7)*2.
  const int mloc = tid >> 3;
  const int m = b0 + mloc;
  const int q2 = (tid & 7) * 2;
  float bs[4][2];
#pragma unroll
  for (int gg = 0; gg < 4; ++gg)
#pragma unroll
    for (int k = 0; k < 2; ++k)
      bs[gg][k] = bi[gg * 512 + ch0 + q2 + k] + bh[gg * 512 + ch0 + q2 + k];
  float cst[2] = {0.f, 0.f};

  unsigned* fl_own = flags + ((size_t)layer * 2 + beta) * 32;  // this WG's gang
  unsigned* fl_src = flags + (size_t)beta * 32;                // layer-1 gang, same beta

  // Per-lane poll assignment. Layer 0: all lanes poll own gang (value >= t means
  // h(t-1) complete). Layer 1: lanes 0..31 poll source gang (>= t+1: h1(t) ready),
  // lanes 32..63 poll own gang (>= t: h2(t-1) ready).
  const unsigned* myfw;
  int tgt_off;
  if (layer == 0)      { myfw = fl_own + (l & 31); tgt_off = 0; }
  else if (l < 32)     { myfw = fl_src + l;        tgt_off = 1; }
  else                 { myfw = fl_own + (l - 32); tgt_off = 0; }

  __shared__ float Gs[4][32][17];

  for (int t = 0; t < TT; ++t) {
    f32x4 acc[2] = {};

    auto gemm = [&](const bf16* A, const s16x8* w) {
#pragma unroll
      for (int kq = 0; kq < 16; ++kq) {
#pragma unroll
        for (int mi = 0; mi < 2; ++mi) {
          s16x8 a = ld8(A + (size_t)(b0 + mi * 16 + lr) * 512 + kq * 32 + lk);
          acc[mi] = __builtin_amdgcn_mfma_f32_16x16x32_bf16(a, w[kq], acc[mi], 0, 0, 0);
        }
      }
    };
    auto poll = [&]() {
      const unsigned tgt = (unsigned)(t + tgt_off);
      for (;;) {
        unsigned v = __hip_atomic_load(myfw, __ATOMIC_RELAXED, __HIP_MEMORY_SCOPE_AGENT);
        if (!__any((int)(v < tgt))) break;
        __builtin_amdgcn_s_sleep(1);
      }
    };

    if (layer == 0) {
      // x-GEMM has no cross-WG dependency: compute it BEFORE waiting on h1(t-1).
      gemm(xT + (size_t)t * (BB * CC), wa);
      poll();
      if (t > 0) gemm(h1h + (size_t)(t - 1) * (BB * HH), wb);
    } else {
      poll();
      gemm(h1h + (size_t)t * (BB * HH), wa);
      if (t > 0) gemm(h2h + (size_t)(t - 1) * (BB * HH), wb);
    }

    // Exchange gate tiles across waves: wave g holds gate g for 32 b x 16 ch.
#pragma unroll
    for (int mi = 0; mi < 2; ++mi)
#pragma unroll
      for (int r = 0; r < 4; ++r)
        Gs[g][mi * 16 + (l >> 4) * 4 + r][lr] = acc[mi][r];
    __syncthreads();

    // Cell update: 2 channels of one batch per thread; c-state in registers.
    bf16* hout = (layer ? h2h : h1h) + (size_t)t * (BB * HH);
    union { ushort u[2]; unsigned v; } pk;
#pragma unroll
    for (int k = 0; k < 2; ++k) {
      int cc = q2 + k;
      float gi = sigm(Gs[0][mloc][cc] + bs[0][k]);
      float gf = sigm(Gs[1][mloc][cc] + bs[1][k]);
      float gg = tanh_fast(Gs[2][mloc][cc] + bs[2][k]);
      float go = sigm(Gs[3][mloc][cc] + bs[3][k]);
      float cv = gf * cst[k] + gi * gg;
      cst[k] = cv;
      float hvf = go * tanh_fast(cv);
      bf16 hb = __float2bfloat16(hvf);
      pk.u[k] = *reinterpret_cast<ushort*>(&hb);
      if (layer) out[((size_t)m * 512 + ch0 + cc) * 512 + t] = hvf;  // write-once, coalesces in L2
    }
    // h square: 4B agent-scope write-through store (lands at coherence point).
    __hip_atomic_store((unsigned*)(hout + (size_t)m * 512 + ch0 + q2), pk.v,
                       __ATOMIC_RELAXED, __HIP_MEMORY_SCOPE_AGENT);

    // Drain this wave's stores, sync WG, then ONE flag store (no RMW).
    asm volatile("s_waitcnt vmcnt(0)" ::: "memory");
    __syncthreads();
    if (tid == 0)
      __hip_atomic_store(fl_own + (blockIdx.x & 31), (unsigned)(t + 1),
                         __ATOMIC_RELAXED, __HIP_MEMORY_SCOPE_AGENT);
  }
}

extern "C" void kernel_launch(void* const* d_in, const int* in_sizes, int n_in,
                              void* d_out, int out_size, void* d_ws, size_t ws_size,
                              hipStream_t stream) {
  const float* x    = (const float*)d_in[0];
  const float* Wih1 = (const float*)d_in[1];
  const float* Whh1 = (const float*)d_in[2];
  const float* bih1 = (const float*)d_in[3];
  const float* bhh1 = (const float*)d_in[4];
  const float* Wih2 = (const float*)d_in[5];
  const float* Whh2 = (const float*)d_in[6];
  const float* bih2 = (const float*)d_in[7];
  const float* bhh2 = (const float*)d_in[8];
  float* out = (float*)d_out;

  // Workspace layout (~104 MB + 512B flags)
  const size_t MB = 1ull << 20;
  char* p = (char*)d_ws;
  bf16*     xT    = (bf16*)(p);               // 32MB (T,B,C)
  bf16*     h1h   = (bf16*)(p + 32 * MB);     // 32MB (T,B,H) history
  bf16*     h2h   = (bf16*)(p + 64 * MB);     // 32MB (T,B,H) history
  bf16*     W1i   = (bf16*)(p + 96 * MB);     // 2MB each
  bf16*     W1h   = (bf16*)(p + 98 * MB);
  bf16*     W2i   = (bf16*)(p + 100 * MB);
  bf16*     W2h   = (bf16*)(p + 102 * MB);
  unsigned* flags = (unsigned*)(p + 104 * MB);  // [2][2][32] u32 = 512B
  if (ws_size < 104 * MB + 512) return;

  const int NW = 4 * HH * CC;  // 1048576 elements per weight matrix
  cast_w_kernel<<<1024, 256, 0, stream>>>(Wih1, W1i, NW);
  cast_w_kernel<<<1024, 256, 0, stream>>>(Whh1, W1h, NW);
  cast_w_kernel<<<1024, 256, 0, stream>>>(Wih2, W2i, NW);
  cast_w_kernel<<<1024, 256, 0, stream>>>(Whh2, W2h, NW);
  transpose_x_kernel<<<dim3(16, 16, 64), dim3(32, 8), 0, stream>>>(x, xT);
  zero_ws_kernel<<<1, 128, 0, stream>>>(flags, 128);

  lstm_persist_kernel<<<128, 256, 0, stream>>>(W1i, W1h, bih1, bhh1,
                                               W2i, W2h, bih2, bhh2,
                                               xT, h1h, h2h, out, flags);
}